// Round 1
// baseline (1602.535 us; speedup 1.0000x reference)
//
#include <hip/hip_runtime.h>

#define NG   4096   // graphs
#define P    24     // nodes per graph
#define EPG  192    // regular edges per graph (P*DEG)
#define ESL  216    // + P self loops
#define DIN  32
#define H    128
#define EX   8
#define NOUT 3
#define STRIDE 132  // padded feature stride (breaks bank conflicts, keeps 16B align)

__device__ __forceinline__ float lrelu(float v, float s) { return v > 0.f ? v : v * s; }

__global__ __launch_bounds__(256, 2) void gat_all(
    const float* __restrict__ x,
    const int*   __restrict__ src,
    const int*   __restrict__ dst,
    const float* __restrict__ extra,
    const float* __restrict__ W0,  const float* __restrict__ b0,
    const float* __restrict__ W1,  const float* __restrict__ b1,
    const float* __restrict__ Wl,  const float* __restrict__ bl,
    const float* __restrict__ Wr,  const float* __restrict__ br,
    const float* __restrict__ att, const float* __restrict__ cbias,
    const float* __restrict__ Wf0, const float* __restrict__ bf0,
    const float* __restrict__ Wf1, const float* __restrict__ bf1,
    const float* __restrict__ Wf2, const float* __restrict__ bf2,
    float* __restrict__ out)
{
    __shared__ float hs [P][H];        // node features (no pad: broadcast reads only)
    __shared__ float xls[P][STRIDE];   // lin_l output (also stages x at start)
    __shared__ float xrs[P][STRIDE];   // lin_r output (also init-MLP temp)
    __shared__ float att_s[H];
    __shared__ float logit[ESL];       // logits -> alpha -> (later) z buffer
    __shared__ unsigned char  es[ESL], ed[ESL];
    __shared__ unsigned short elist[ESL];
    __shared__ int eoff[P + 1];
    __shared__ int ecnt[P];

    const int g  = blockIdx.x;
    const int t  = threadIdx.x;
    const int j  = t & (H - 1);     // output column
    const int nh = t >> 7;          // node half: 0 -> nodes 0..11, 1 -> 12..23
    const int n0 = nh * (P / 2);
    const long long gnode = (long long)g * P;

    // ---------- stage x, build edge CSR (structure constant across convs) ----
    if (t < P) ecnt[t] = 0;
    for (int i = t; i < P * DIN; i += 256) {
        int n = i >> 5, k = i & 31;
        xls[n][k] = x[(gnode + n) * DIN + k];
    }
    __syncthreads();

    if (t < ESL) {
        int s, d;
        if (t < EPG) {
            s = src[(long long)g * EPG + t] - (int)gnode;
            d = dst[(long long)g * EPG + t] - (int)gnode;
        } else {
            s = d = t - EPG;        // self loop
        }
        es[t] = (unsigned char)s;
        ed[t] = (unsigned char)d;
        atomicAdd(&ecnt[d], 1);
    }
    __syncthreads();
    if (t == 0) {
        int a = 0;
        for (int n = 0; n < P; ++n) { eoff[n] = a; a += ecnt[n]; }
        eoff[P] = a;
    }
    __syncthreads();
    if (t < P) ecnt[t] = 0;
    __syncthreads();
    if (t < ESL) {
        int d = ed[t];
        int pos = atomicAdd(&ecnt[d], 1);
        elist[eoff[d] + pos] = (unsigned short)t;
    }
    // (no barrier needed: elist is next read after several barriers)

    // ---------- init MLP layer 0: hs = LR(x @ W0 + b0, 0.01) ----------
    {
        float acc[P / 2];
        float b = b0[j];
        #pragma unroll
        for (int i = 0; i < P / 2; ++i) acc[i] = b;
        for (int k = 0; k < DIN; ++k) {
            float w = W0[k * H + j];
            #pragma unroll
            for (int i = 0; i < P / 2; ++i) acc[i] += xls[n0 + i][k] * w;
        }
        #pragma unroll
        for (int i = 0; i < P / 2; ++i) hs[n0 + i][j] = lrelu(acc[i], 0.01f);
    }
    __syncthreads();
    // ---------- init MLP layer 1: xrs = LR(hs @ W1 + b1, 0.01), copy back ----
    {
        float acc[P / 2];
        float b = b1[j];
        #pragma unroll
        for (int i = 0; i < P / 2; ++i) acc[i] = b;
        for (int k4 = 0; k4 < H / 4; ++k4) {
            float w0v = W1[(k4 * 4 + 0) * H + j];
            float w1v = W1[(k4 * 4 + 1) * H + j];
            float w2v = W1[(k4 * 4 + 2) * H + j];
            float w3v = W1[(k4 * 4 + 3) * H + j];
            #pragma unroll
            for (int i = 0; i < P / 2; ++i) {
                const float4 hv = *reinterpret_cast<const float4*>(&hs[n0 + i][k4 * 4]);
                acc[i] += hv.x * w0v + hv.y * w1v + hv.z * w2v + hv.w * w3v;
            }
        }
        #pragma unroll
        for (int i = 0; i < P / 2; ++i) xrs[n0 + i][j] = lrelu(acc[i], 0.01f);
    }
    __syncthreads();
    for (int i = t; i < P * H; i += 256) {
        int n = i >> 7, jj = i & (H - 1);
        hs[n][jj] = xrs[n][jj];
    }
    __syncthreads();

    // ---------- 6 GATv2 convs ----------
    for (int c = 0; c < 6; ++c) {
        if (t < H) att_s[t] = att[c * H + t];
        const float* wl = Wl + c * H * H;
        const float* wr = Wr + c * H * H;
        float accl[P / 2], accr[P / 2];
        {
            float bll = bl[c * H + j], brr = br[c * H + j];
            #pragma unroll
            for (int i = 0; i < P / 2; ++i) { accl[i] = bll; accr[i] = brr; }
        }
        for (int k4 = 0; k4 < H / 4; ++k4) {
            float wl0 = wl[(k4 * 4 + 0) * H + j];
            float wl1 = wl[(k4 * 4 + 1) * H + j];
            float wl2 = wl[(k4 * 4 + 2) * H + j];
            float wl3 = wl[(k4 * 4 + 3) * H + j];
            float wr0 = wr[(k4 * 4 + 0) * H + j];
            float wr1 = wr[(k4 * 4 + 1) * H + j];
            float wr2 = wr[(k4 * 4 + 2) * H + j];
            float wr3 = wr[(k4 * 4 + 3) * H + j];
            #pragma unroll
            for (int i = 0; i < P / 2; ++i) {
                const float4 hv = *reinterpret_cast<const float4*>(&hs[n0 + i][k4 * 4]);
                accl[i] += hv.x * wl0 + hv.y * wl1 + hv.z * wl2 + hv.w * wl3;
                accr[i] += hv.x * wr0 + hv.y * wr1 + hv.z * wr2 + hv.w * wr3;
            }
        }
        #pragma unroll
        for (int i = 0; i < P / 2; ++i) {
            xls[n0 + i][j] = accl[i];
            xrs[n0 + i][j] = accr[i];
        }
        __syncthreads();

        // per-edge attention logits: att . LR(xl[src] + xr[dst], 0.2)
        if (t < ESL) {
            int s = es[t], d = ed[t];
            float acc = 0.f;
            for (int k4 = 0; k4 < H / 4; ++k4) {
                const float4 a  = *reinterpret_cast<const float4*>(&xls[s][k4 * 4]);
                const float4 b  = *reinterpret_cast<const float4*>(&xrs[d][k4 * 4]);
                const float4 av = *reinterpret_cast<const float4*>(&att_s[k4 * 4]);
                acc += lrelu(a.x + b.x, 0.2f) * av.x;
                acc += lrelu(a.y + b.y, 0.2f) * av.y;
                acc += lrelu(a.z + b.z, 0.2f) * av.z;
                acc += lrelu(a.w + b.w, 0.2f) * av.w;
            }
            logit[t] = acc;
        }
        __syncthreads();

        // segment softmax over incoming edges per dst node
        if (t < P) {
            int o0 = eoff[t], o1 = eoff[t + 1];
            float m = -1e30f;
            for (int q = o0; q < o1; ++q) m = fmaxf(m, logit[elist[q]]);
            float ssum = 0.f;
            for (int q = o0; q < o1; ++q) {
                int e = elist[q];
                float ex = __expf(logit[e] - m);
                logit[e] = ex;
                ssum += ex;
            }
            float inv = 1.f / ssum;
            for (int q = o0; q < o1; ++q) logit[elist[q]] *= inv;
        }
        __syncthreads();

        // aggregate: h[n] = sum_in xl[src]*alpha + cbias  (+ LR except convs 2,5)
        {
            float cb = cbias[c * H + j];
            bool doact = (c % 3) < 2;
            #pragma unroll
            for (int i = 0; i < P / 2; ++i) {
                int n = n0 + i;
                float acc = cb;
                for (int q = eoff[n]; q < eoff[n + 1]; ++q) {
                    int e = elist[q];
                    acc += xls[es[e]][j] * logit[e];
                }
                hs[n][j] = doact ? lrelu(acc, 0.01f) : acc;
            }
        }
        __syncthreads();
    }

    // ---------- global_add_pool + concat(extra) + head MLP ----------
    float* zbuf = logit;            // 216 floats >= 136 needed
    if (nh == 0) {
        float p = 0.f;
        #pragma unroll
        for (int n = 0; n < P; ++n) p += hs[n][j];
        zbuf[j] = p;
    }
    if (t < EX) zbuf[H + t] = extra[(long long)g * EX + t];
    __syncthreads();
    if (nh == 0) {
        float a = bf0[j];
        for (int k = 0; k < H + EX; ++k) a += zbuf[k] * Wf0[k * H + j];
        att_s[j] = lrelu(a, 0.01f);
    }
    __syncthreads();
    if (nh == 0) {
        float a = bf1[j];
        for (int k = 0; k < H; ++k) a += att_s[k] * Wf1[k * H + j];
        zbuf[j] = lrelu(a, 0.01f);
    }
    __syncthreads();
    if (t < NOUT) {
        float a = bf2[t];
        for (int k = 0; k < H; ++k) a += zbuf[k] * Wf2[k * NOUT + t];
        out[(long long)g * NOUT + t] = a;
    }
}

extern "C" void kernel_launch(void* const* d_in, const int* in_sizes, int n_in,
                              void* d_out, int out_size, void* d_ws, size_t ws_size,
                              hipStream_t stream) {
    const float* x     = (const float*)d_in[0];
    const int*   src   = (const int*)  d_in[1];
    const int*   dst   = (const int*)  d_in[2];
    // d_in[3] = batch (int32) — implied by node index (i / P), unused
    const float* extra = (const float*)d_in[4];
    const float* W0    = (const float*)d_in[5];
    const float* b0    = (const float*)d_in[6];
    const float* W1    = (const float*)d_in[7];
    const float* b1    = (const float*)d_in[8];
    const float* Wl    = (const float*)d_in[9];
    const float* bl    = (const float*)d_in[10];
    const float* Wr    = (const float*)d_in[11];
    const float* br    = (const float*)d_in[12];
    const float* att   = (const float*)d_in[13];
    const float* cbias = (const float*)d_in[14];
    const float* Wf0   = (const float*)d_in[15];
    const float* bf0   = (const float*)d_in[16];
    const float* Wf1   = (const float*)d_in[17];
    const float* bf1   = (const float*)d_in[18];
    const float* Wf2   = (const float*)d_in[19];
    const float* bf2   = (const float*)d_in[20];
    float* out = (float*)d_out;

    gat_all<<<NG, 256, 0, stream>>>(x, src, dst, extra,
                                    W0, b0, W1, b1,
                                    Wl, bl, Wr, br, att, cbias,
                                    Wf0, bf0, Wf1, bf1, Wf2, bf2, out);
}

// Round 2
// 449.775 us; speedup vs baseline: 3.5630x; 3.5630x over previous
//
#include <hip/hip_runtime.h>

#define NG   4096
#define P    24
#define EPG  192
#define ESL  216
#define DIN  32
#define H    128
#define EX   8
#define NOUT 3
#define HSS  136   // bf16 row stride for [32][H] tiles (272B: spreads bank classes)

typedef short bf16x8 __attribute__((ext_vector_type(8)));
typedef float f32x4  __attribute__((ext_vector_type(4)));

__device__ __forceinline__ float bf2f(unsigned short u) {
    return __uint_as_float(((unsigned)u) << 16);
}
__device__ __forceinline__ unsigned short f2bf(float v) {   // round-to-nearest-even
    unsigned u = __float_as_uint(v);
    unsigned r = u + 0x7fffu + ((u >> 16) & 1u);
    return (unsigned short)(r >> 16);
}
__device__ __forceinline__ float lrelu(float v, float s) { return v > 0.f ? v : v * s; }

// ---- weight convert+transpose pre-pass:  ws layout (ushort elements) ----
// W0T [128][32]  @ 0        (4096)
// W1T [128][128] @ 4096     (16384)
// WlT [6][128][128] @ 20480 (98304)
// WrT [6][128][128] @ 118784(98304)   total 217088 ushort = 434176 B
__global__ void cvtw(const float* __restrict__ W0, const float* __restrict__ W1,
                     const float* __restrict__ Wl, const float* __restrict__ Wr,
                     unsigned short* __restrict__ ws) {
    int i = blockIdx.x * 256 + threadIdx.x;
    float v;
    if (i < 4096)            { int n = i >> 5, k = i & 31;  v = W0[k * 128 + n]; }
    else if (i < 20480)      { int j = i - 4096;  int n = j >> 7, k = j & 127; v = W1[k * 128 + n]; }
    else if (i < 118784)     { int j = i - 20480; int c = j >> 14, r = j & 16383;
                               int n = r >> 7, k = r & 127; v = Wl[c * 16384 + k * 128 + n]; }
    else if (i < 217088)     { int j = i - 118784; int c = j >> 14, r = j & 16383;
                               int n = r >> 7, k = r & 127; v = Wr[c * 16384 + k * 128 + n]; }
    else return;
    ws[i] = f2bf(v);
}

__global__ __launch_bounds__(256, 3) void gat_all(
    const float* __restrict__ x,
    const int*   __restrict__ src,
    const int*   __restrict__ dst,
    const float* __restrict__ extra,
    const float* __restrict__ b0,  const float* __restrict__ b1,
    const float* __restrict__ bl,  const float* __restrict__ br,
    const float* __restrict__ att, const float* __restrict__ cbias,
    const float* __restrict__ Wf0, const float* __restrict__ bf0,
    const float* __restrict__ Wf1, const float* __restrict__ bf1,
    const float* __restrict__ Wf2, const float* __restrict__ bf2,
    const unsigned short* __restrict__ wsb,
    float* __restrict__ out)
{
    __shared__ unsigned short hs [32 * HSS];   // node features bf16 (rows 24-31 pad)
    __shared__ unsigned short xls[32 * HSS];   // lin_l out bf16 (also init tmp)
    __shared__ unsigned short xrs[32 * HSS];   // lin_r out bf16
    __shared__ unsigned short xlT[128 * 32];   // xl transposed bf16 (also x-stage)
    __shared__ float          Amat[1024];      // alpha matrix f32 (also head scratch)
    __shared__ unsigned short Amb [1024];      // alpha matrix bf16
    __shared__ float att_s[H];
    __shared__ float dsum[P];
    __shared__ unsigned char es_[ESL], ed_[ESL];

    const int g    = blockIdx.x;
    const int t    = threadIdx.x;
    const int lane = t & 63;
    const int w    = t >> 6;          // wave 0..3
    const int m16  = lane & 15;
    const int kc   = lane >> 4;       // 0..3
    const long long gn = (long long)g * P;

    const unsigned short* W0T = wsb;
    const unsigned short* W1T = wsb + 4096;
    const unsigned short* WLT = wsb + 20480;
    const unsigned short* WRT = wsb + 118784;

    // ---------------- stage edges + x (bf16, into xlT buffer [32][32]) -------
    if (t < ESL) {
        int s, d;
        if (t < EPG) {
            s = src[(long long)g * EPG + t] - (int)gn;
            d = dst[(long long)g * EPG + t] - (int)gn;
        } else { s = d = t - EPG; }
        es_[t] = (unsigned char)s;
        ed_[t] = (unsigned char)d;
    }
    {
        unsigned short* xB = xlT;
        if (t < 192) {
            float4 v = *reinterpret_cast<const float4*>(&x[gn * DIN + t * 4]);
            ushort4 u = make_ushort4(f2bf(v.x), f2bf(v.y), f2bf(v.z), f2bf(v.w));
            *reinterpret_cast<ushort4*>(&xB[t * 4]) = u;
        } else {
            *reinterpret_cast<ushort4*>(&xB[768 + (t - 192) * 4]) = make_ushort4(0, 0, 0, 0);
        }
    }
    __syncthreads();

    // ---------------- init MLP layer 0: xls = LR(x @ W0 + b0) ----------------
    {
        f32x4 acc[4] = {};
        bf16x8 a = *reinterpret_cast<const bf16x8*>(&xlT[((w & 1) * 16 + m16) * 32 + kc * 8]);
        #pragma unroll
        for (int i = 0; i < 4; ++i) {
            int nt = (w >> 1) * 4 + i;
            bf16x8 b = *reinterpret_cast<const bf16x8*>(&W0T[(nt * 16 + m16) * 32 + kc * 8]);
            acc[i] = __builtin_amdgcn_mfma_f32_16x16x32_bf16(a, b, acc[i], 0, 0, 0);
        }
        #pragma unroll
        for (int i = 0; i < 4; ++i) {
            int col = (w >> 1) * 64 + i * 16 + m16;
            float bv = b0[col];
            #pragma unroll
            for (int r = 0; r < 4; ++r) {
                int row = (w & 1) * 16 + kc * 4 + r;
                xls[row * HSS + col] = f2bf(lrelu(acc[i][r] + bv, 0.01f));
            }
        }
    }
    __syncthreads();

    // ---------------- init MLP layer 1: hs = LR(xls @ W1 + b1) ---------------
    {
        f32x4 acc[4] = {};
        for (int kt = 0; kt < 4; ++kt) {
            bf16x8 a = *reinterpret_cast<const bf16x8*>(&xls[((w & 1) * 16 + m16) * HSS + kt * 32 + kc * 8]);
            #pragma unroll
            for (int i = 0; i < 4; ++i) {
                int nt = (w >> 1) * 4 + i;
                bf16x8 b = *reinterpret_cast<const bf16x8*>(&W1T[(nt * 16 + m16) * 128 + kt * 32 + kc * 8]);
                acc[i] = __builtin_amdgcn_mfma_f32_16x16x32_bf16(a, b, acc[i], 0, 0, 0);
            }
        }
        #pragma unroll
        for (int i = 0; i < 4; ++i) {
            int col = (w >> 1) * 64 + i * 16 + m16;
            float bv = b1[col];
            #pragma unroll
            for (int r = 0; r < 4; ++r) {
                int row = (w & 1) * 16 + kc * 4 + r;
                hs[row * HSS + col] = f2bf(lrelu(acc[i][r] + bv, 0.01f));
            }
        }
    }
    __syncthreads();

    // ---------------- 6 GATv2 convs ----------------
    for (int c = 0; c < 6; ++c) {
        if (t < H)  att_s[t] = att[c * H + t];
        if (t < P)  dsum[t] = 0.f;
        *reinterpret_cast<float4*>(&Amat[t * 4]) = make_float4(0.f, 0.f, 0.f, 0.f);

        // xl = hs@Wl + bl  /  xr = hs@Wr + br  (wave parity picks matrix)
        const unsigned short* WT   = ((w & 1) ? WRT : WLT) + c * 16384;
        const float*          bias = ((w & 1) ? br : bl) + c * H;
        f32x4 acc[8] = {};
        for (int kt = 0; kt < 4; ++kt) {
            bf16x8 a0 = *reinterpret_cast<const bf16x8*>(&hs[(m16)      * HSS + kt * 32 + kc * 8]);
            bf16x8 a1 = *reinterpret_cast<const bf16x8*>(&hs[(16 + m16) * HSS + kt * 32 + kc * 8]);
            #pragma unroll
            for (int i = 0; i < 4; ++i) {
                int nt = (w >> 1) * 4 + i;
                bf16x8 b = *reinterpret_cast<const bf16x8*>(&WT[(nt * 16 + m16) * 128 + kt * 32 + kc * 8]);
                acc[i]     = __builtin_amdgcn_mfma_f32_16x16x32_bf16(a0, b, acc[i],     0, 0, 0);
                acc[4 + i] = __builtin_amdgcn_mfma_f32_16x16x32_bf16(a1, b, acc[4 + i], 0, 0, 0);
            }
        }
        {
            unsigned short* XO = (w & 1) ? xrs : xls;
            const bool isL = !(w & 1);
            #pragma unroll
            for (int mt = 0; mt < 2; ++mt)
            #pragma unroll
            for (int i = 0; i < 4; ++i) {
                int col = (w >> 1) * 64 + i * 16 + m16;
                float bv = bias[col];
                #pragma unroll
                for (int r = 0; r < 4; ++r) {
                    int row = mt * 16 + kc * 4 + r;
                    unsigned short ub = f2bf(acc[mt * 4 + i][r] + bv);
                    XO[row * HSS + col] = ub;
                    if (isL) xlT[col * 32 + row] = ub;   // transposed copy for aggregate
                }
            }
        }
        __syncthreads();

        // edge logits + exp (no max-sub: logits bounded, alpha invariant)
        float ex = 0.f; int sd_s = 0, sd_d = 0;
        if (t < ESL) {
            sd_s = es_[t]; sd_d = ed_[t];
            const unsigned short* xa = &xls[sd_s * HSS];
            const unsigned short* xb = &xrs[sd_d * HSS];
            float lg = 0.f;
            for (int cc = 0; cc < 16; ++cc) {
                bf16x8 a = *reinterpret_cast<const bf16x8*>(&xa[cc * 8]);
                bf16x8 b = *reinterpret_cast<const bf16x8*>(&xb[cc * 8]);
                #pragma unroll
                for (int q = 0; q < 8; ++q) {
                    float u = bf2f((unsigned short)a[q]) + bf2f((unsigned short)b[q]);
                    u = lrelu(u, 0.2f);
                    lg += u * att_s[cc * 8 + q];
                }
            }
            ex = __expf(lg);
            atomicAdd(&dsum[sd_d], ex);
        }
        __syncthreads();
        if (t < ESL) {
            float alpha = ex / dsum[sd_d];
            atomicAdd(&Amat[sd_d * 32 + sd_s], alpha);
        }
        __syncthreads();
        {   // convert alpha matrix to bf16
            float4 v = *reinterpret_cast<const float4*>(&Amat[t * 4]);
            ushort4 u = make_ushort4(f2bf(v.x), f2bf(v.y), f2bf(v.z), f2bf(v.w));
            *reinterpret_cast<ushort4*>(&Amb[t * 4]) = u;
        }
        __syncthreads();

        // aggregate: hs = Amat @ xl + cbias  (+ LR except convs 2,5)
        {
            f32x4 acc2[4] = {};
            bf16x8 a = *reinterpret_cast<const bf16x8*>(&Amb[((w & 1) * 16 + m16) * 32 + kc * 8]);
            #pragma unroll
            for (int i = 0; i < 4; ++i) {
                int nt = (w >> 1) * 4 + i;
                bf16x8 b = *reinterpret_cast<const bf16x8*>(&xlT[(nt * 16 + m16) * 32 + kc * 8]);
                acc2[i] = __builtin_amdgcn_mfma_f32_16x16x32_bf16(a, b, acc2[i], 0, 0, 0);
            }
            const bool doact = (c % 3) < 2;
            #pragma unroll
            for (int i = 0; i < 4; ++i) {
                int col = (w >> 1) * 64 + i * 16 + m16;
                float cb = cbias[c * H + col];
                #pragma unroll
                for (int r = 0; r < 4; ++r) {
                    int row = (w & 1) * 16 + kc * 4 + r;
                    float v = acc2[i][r] + cb;
                    if (doact) v = lrelu(v, 0.01f);
                    hs[row * HSS + col] = f2bf(v);
                }
            }
        }
        __syncthreads();
    }

    // ---------------- pool + head MLP (f32, Amat reused as scratch) ----------
    float* z  = Amat;         // 136
    float* pa = Amat + 144;   // 128
    float* pb = Amat + 288;
    float* h1 = Amat + 432;
    float* qa = Amat + 576;
    float* qb = Amat + 720;
    float* h2 = Amat + 864;
    if (t < H) {
        float s = 0.f;
        for (int r = 0; r < P; ++r) s += bf2f(hs[r * HSS + t]);
        z[t] = s;
    } else if (t < H + EX) {
        z[t] = extra[(long long)g * EX + (t - H)];
    }
    __syncthreads();
    {
        int j = t & 127, half = t >> 7;
        float a = half ? 0.f : bf0[j];
        int k0 = half ? 68 : 0, k1 = half ? 136 : 68;
        for (int k = k0; k < k1; ++k) a += z[k] * Wf0[k * H + j];
        (half ? pb : pa)[j] = a;
    }
    __syncthreads();
    if (t < H) h1[t] = lrelu(pa[t] + pb[t], 0.01f);
    __syncthreads();
    {
        int j = t & 127, half = t >> 7;
        float a = half ? 0.f : bf1[j];
        int k0 = half * 64, k1 = k0 + 64;
        for (int k = k0; k < k1; ++k) a += h1[k] * Wf1[k * H + j];
        (half ? qb : qa)[j] = a;
    }
    __syncthreads();
    if (t < H) h2[t] = lrelu(qa[t] + qb[t], 0.01f);
    __syncthreads();
    if (t < NOUT) {
        float a = bf2[t];
        for (int k = 0; k < H; ++k) a += h2[k] * Wf2[k * NOUT + t];
        out[(long long)g * NOUT + t] = a;
    }
}

extern "C" void kernel_launch(void* const* d_in, const int* in_sizes, int n_in,
                              void* d_out, int out_size, void* d_ws, size_t ws_size,
                              hipStream_t stream) {
    (void)in_sizes; (void)n_in; (void)out_size; (void)ws_size;
    const float* x     = (const float*)d_in[0];
    const int*   src   = (const int*)  d_in[1];
    const int*   dst   = (const int*)  d_in[2];
    const float* extra = (const float*)d_in[4];
    const float* W0    = (const float*)d_in[5];
    const float* b0    = (const float*)d_in[6];
    const float* W1    = (const float*)d_in[7];
    const float* b1    = (const float*)d_in[8];
    const float* Wl    = (const float*)d_in[9];
    const float* bl    = (const float*)d_in[10];
    const float* Wr    = (const float*)d_in[11];
    const float* br    = (const float*)d_in[12];
    const float* att   = (const float*)d_in[13];
    const float* cbias = (const float*)d_in[14];
    const float* Wf0   = (const float*)d_in[15];
    const float* bf0   = (const float*)d_in[16];
    const float* Wf1   = (const float*)d_in[17];
    const float* bf1   = (const float*)d_in[18];
    const float* Wf2   = (const float*)d_in[19];
    const float* bf2   = (const float*)d_in[20];
    unsigned short* wsb = (unsigned short*)d_ws;
    float* out = (float*)d_out;

    cvtw<<<848, 256, 0, stream>>>(W0, W1, Wl, Wr, wsb);
    gat_all<<<NG, 256, 0, stream>>>(x, src, dst, extra, b0, b1, bl, br, att, cbias,
                                    Wf0, bf0, Wf1, bf1, Wf2, bf2, wsb, out);
}

// Round 3
// 394.610 us; speedup vs baseline: 4.0611x; 1.1398x over previous
//
#include <hip/hip_runtime.h>

#define NG   4096
#define P    24
#define EPG  192
#define ESL  216
#define DIN  32
#define H    128
#define EX   8
#define NOUT 3
#define HSS  136   // bf16 row stride for [32][H] tiles (272B rows)
#define XTS  40    // xlT row stride in ushorts (80B rows, 16B-aligned)

typedef short bf16x8 __attribute__((ext_vector_type(8)));
typedef float f32x4  __attribute__((ext_vector_type(4)));

__device__ __forceinline__ float u2f(unsigned u) { return __uint_as_float(u); }
__device__ __forceinline__ unsigned short f2bf(float v) {   // round-to-nearest-even
    unsigned u = __float_as_uint(v);
    unsigned r = u + 0x7fffu + ((u >> 16) & 1u);
    return (unsigned short)(r >> 16);
}
__device__ __forceinline__ float lrelu(float v, float s) { return v > 0.f ? v : v * s; }

// ---- weight convert+transpose pre-pass (ushort elements in d_ws) ----
// W0T [128][32] @0 (4096) | W1T [128][128] @4096 (16384)
// WlT [6][128][128] @20480 | WrT [6][128][128] @118784  -> 217088 total
__global__ void cvtw(const float* __restrict__ W0, const float* __restrict__ W1,
                     const float* __restrict__ Wl, const float* __restrict__ Wr,
                     unsigned short* __restrict__ ws) {
    int i = blockIdx.x * 256 + threadIdx.x;
    float v;
    if (i < 4096)            { int n = i >> 5, k = i & 31;  v = W0[k * 128 + n]; }
    else if (i < 20480)      { int j = i - 4096;  int n = j >> 7, k = j & 127; v = W1[k * 128 + n]; }
    else if (i < 118784)     { int j = i - 20480; int c = j >> 14, r = j & 16383;
                               int n = r >> 7, k = r & 127; v = Wl[c * 16384 + k * 128 + n]; }
    else if (i < 217088)     { int j = i - 118784; int c = j >> 14, r = j & 16383;
                               int n = r >> 7, k = r & 127; v = Wr[c * 16384 + k * 128 + n]; }
    else return;
    ws[i] = f2bf(v);
}

#define EDGE_PAIR(wa, wb, p, q)                                   \
    do {                                                          \
        float a0_ = u2f((wa) << 16);                              \
        float a1_ = u2f((wa) & 0xffff0000u);                      \
        float b0_ = u2f((wb) << 16);                              \
        float b1_ = u2f((wb) & 0xffff0000u);                      \
        abss = fmaf(fabsf(a0_ + b0_), (p), abss);                 \
        abss = fmaf(fabsf(a1_ + b1_), (q), abss);                 \
    } while (0)

#define DOT_PAIR(wv, p, q)                                        \
    do {                                                          \
        sum = fmaf(u2f((wv) << 16), (p), sum);                    \
        sum = fmaf(u2f((wv) & 0xffff0000u), (q), sum);            \
    } while (0)

__global__ __launch_bounds__(256, 4) void gat_all(
    const float* __restrict__ x,
    const int*   __restrict__ src,
    const int*   __restrict__ dst,
    const float* __restrict__ extra,
    const float* __restrict__ b0,  const float* __restrict__ b1,
    const float* __restrict__ bl,  const float* __restrict__ br,
    const float* __restrict__ att, const float* __restrict__ cbias,
    const float* __restrict__ Wf0, const float* __restrict__ bf0,
    const float* __restrict__ Wf1, const float* __restrict__ bf1,
    const float* __restrict__ Wf2, const float* __restrict__ bf2,
    const unsigned short* __restrict__ wsb,
    float* __restrict__ out)
{
    // LDS budget: 8704*3 + 10240 + 4096 + 512 = 40960 B exactly -> 4 blocks/CU
    __shared__ __align__(16) unsigned short hb [32 * HSS];  // node features bf16
    __shared__ __align__(16) unsigned short xlb[32 * HSS];  // lin_l out bf16
    __shared__ __align__(16) unsigned short xrb[32 * HSS];  // lin_r out bf16
    __shared__ __align__(16) unsigned short xlT[128 * XTS]; // xl^T bf16 (+x stage)
    __shared__ __align__(16) float          Am[1024];       // alpha f32 [24][32]; rows 24-31 = misc
    __shared__ __align__(16) float          att_s[H];

    float* dsum = Am + 768;   // 24 floats (inside Am pad rows; finite garbage OK)
    float* slr  = Am + 792;   // 48 floats: slr[2n]=xl[n].att, slr[2n+1]=xr[n].att

    const int g    = blockIdx.x;
    const int t    = threadIdx.x;
    const int lane = t & 63;
    const int w    = t >> 6;
    const int m16  = lane & 15;
    const int kc   = lane >> 4;
    const long long gn = (long long)g * P;

    const unsigned short* W0T = wsb;
    const unsigned short* W1T = wsb + 4096;
    const unsigned short* WLT = wsb + 20480;
    const unsigned short* WRT = wsb + 118784;

    // edge endpoints live in registers for the whole kernel
    int s_e = 0, d_e = 0;
    if (t < ESL) {
        if (t < EPG) {
            s_e = src[(long long)g * EPG + t] - (int)gn;
            d_e = dst[(long long)g * EPG + t] - (int)gn;
        } else { s_e = d_e = t - EPG; }
    }

    // stage x (bf16) into xlT as [32 nodes][32 feat], stride XTS
    if (t < 192) {
        float4 v = *reinterpret_cast<const float4*>(&x[gn * DIN + t * 4]);
        int n = t >> 3, k = (t & 7) * 4;
        *reinterpret_cast<ushort4*>(&xlT[n * XTS + k]) =
            make_ushort4(f2bf(v.x), f2bf(v.y), f2bf(v.z), f2bf(v.w));
    } else {
        int u = t - 192;                       // zero pad rows 24-31
        int r = 24 + (u >> 3), k = (u & 7) * 4;
        *reinterpret_cast<ushort4*>(&xlT[r * XTS + k]) = make_ushort4(0, 0, 0, 0);
    }
    __syncthreads();

    // ---------------- init MLP layer 0: xlb = LR(x @ W0 + b0) ----------------
    {
        f32x4 acc[4] = {};
        bf16x8 a = *reinterpret_cast<const bf16x8*>(&xlT[((w & 1) * 16 + m16) * XTS + kc * 8]);
        #pragma unroll
        for (int i = 0; i < 4; ++i) {
            int nt = (w >> 1) * 4 + i;
            bf16x8 b = *reinterpret_cast<const bf16x8*>(&W0T[(nt * 16 + m16) * 32 + kc * 8]);
            acc[i] = __builtin_amdgcn_mfma_f32_16x16x32_bf16(a, b, acc[i], 0, 0, 0);
        }
        #pragma unroll
        for (int i = 0; i < 4; ++i) {
            int col = (w >> 1) * 64 + i * 16 + m16;
            float bv = b0[col];
            #pragma unroll
            for (int r = 0; r < 4; ++r) {
                int row = (w & 1) * 16 + kc * 4 + r;
                xlb[row * HSS + col] = f2bf(lrelu(acc[i][r] + bv, 0.01f));
            }
        }
    }
    __syncthreads();

    // ---------------- init MLP layer 1: hb = LR(xlb @ W1 + b1) ---------------
    {
        f32x4 acc[4] = {};
        for (int kt = 0; kt < 4; ++kt) {
            bf16x8 a = *reinterpret_cast<const bf16x8*>(&xlb[((w & 1) * 16 + m16) * HSS + kt * 32 + kc * 8]);
            #pragma unroll
            for (int i = 0; i < 4; ++i) {
                int nt = (w >> 1) * 4 + i;
                bf16x8 b = *reinterpret_cast<const bf16x8*>(&W1T[(nt * 16 + m16) * 128 + kt * 32 + kc * 8]);
                acc[i] = __builtin_amdgcn_mfma_f32_16x16x32_bf16(a, b, acc[i], 0, 0, 0);
            }
        }
        #pragma unroll
        for (int i = 0; i < 4; ++i) {
            int col = (w >> 1) * 64 + i * 16 + m16;
            float bv = b1[col];
            #pragma unroll
            for (int r = 0; r < 4; ++r) {
                int row = (w & 1) * 16 + kc * 4 + r;
                hb[row * HSS + col] = f2bf(lrelu(acc[i][r] + bv, 0.01f));
            }
        }
    }
    __syncthreads();

    // ---------------- 6 GATv2 convs ----------------
    for (int c = 0; c < 6; ++c) {
        if (t < H)   att_s[t] = att[c * H + t];
        if (t < 192) *reinterpret_cast<float4*>(&Am[t * 4]) = make_float4(0.f, 0.f, 0.f, 0.f);
        if (t < P)   dsum[t] = 0.f;

        // xl = hb@Wl + bl / xr = hb@Wr + br  (wave parity picks matrix)
        const unsigned short* WT   = ((w & 1) ? WRT : WLT) + c * 16384;
        const float*          bias = ((w & 1) ? br : bl) + c * H;
        f32x4 acc[8] = {};
        for (int kt = 0; kt < 4; ++kt) {
            bf16x8 a0 = *reinterpret_cast<const bf16x8*>(&hb[(m16)      * HSS + kt * 32 + kc * 8]);
            bf16x8 a1 = *reinterpret_cast<const bf16x8*>(&hb[(16 + m16) * HSS + kt * 32 + kc * 8]);
            #pragma unroll
            for (int i = 0; i < 4; ++i) {
                int nt = (w >> 1) * 4 + i;
                bf16x8 b = *reinterpret_cast<const bf16x8*>(&WT[(nt * 16 + m16) * 128 + kt * 32 + kc * 8]);
                acc[i]     = __builtin_amdgcn_mfma_f32_16x16x32_bf16(a0, b, acc[i],     0, 0, 0);
                acc[4 + i] = __builtin_amdgcn_mfma_f32_16x16x32_bf16(a1, b, acc[4 + i], 0, 0, 0);
            }
        }
        {
            unsigned short* XO = (w & 1) ? xrb : xlb;
            const bool isL = !(w & 1);
            #pragma unroll
            for (int mt = 0; mt < 2; ++mt)
            #pragma unroll
            for (int i = 0; i < 4; ++i) {
                int col = (w >> 1) * 64 + i * 16 + m16;
                float bv = bias[col];
                unsigned short ub[4];
                #pragma unroll
                for (int r = 0; r < 4; ++r) {
                    int row = mt * 16 + kc * 4 + r;
                    ub[r] = f2bf(acc[mt * 4 + i][r] + bv);
                    XO[row * HSS + col] = ub[r];
                }
                if (isL)   // transposed copy, vectorized: 4 D-rows are contiguous here
                    *reinterpret_cast<ushort4*>(&xlT[col * XTS + mt * 16 + kc * 4]) =
                        make_ushort4(ub[0], ub[1], ub[2], ub[3]);
            }
        }
        __syncthreads();

        // edge abs-term (t<216) in parallel with per-node att-dots (t>=216)
        float abss = 0.f;
        if (t < ESL) {
            const uint4*  xa = reinterpret_cast<const uint4*>(&xlb[s_e * HSS]);
            const uint4*  xb = reinterpret_cast<const uint4*>(&xrb[d_e * HSS]);
            const float4* ap = reinterpret_cast<const float4*>(att_s);
            #pragma unroll 4
            for (int cc = 0; cc < 16; ++cc) {
                uint4 wa = xa[cc], wb = xb[cc];
                float4 p0 = ap[cc * 2], p1 = ap[cc * 2 + 1];
                EDGE_PAIR(wa.x, wb.x, p0.x, p0.y);
                EDGE_PAIR(wa.y, wb.y, p0.z, p0.w);
                EDGE_PAIR(wa.z, wb.z, p1.x, p1.y);
                EDGE_PAIR(wa.w, wb.w, p1.z, p1.w);
            }
        } else {
            int u = t - ESL;                      // 40 threads, 48 tasks
            const float4* ap = reinterpret_cast<const float4*>(att_s);
            for (int task = u; task < 48; task += 40) {
                int node = task >> 1;
                const uint4* rp = reinterpret_cast<const uint4*>(
                    ((task & 1) ? xrb : xlb) + node * HSS);
                float sum = 0.f;
                #pragma unroll 4
                for (int cc = 0; cc < 16; ++cc) {
                    uint4 wv = rp[cc];
                    float4 p0 = ap[cc * 2], p1 = ap[cc * 2 + 1];
                    DOT_PAIR(wv.x, p0.x, p0.y);
                    DOT_PAIR(wv.y, p0.z, p0.w);
                    DOT_PAIR(wv.z, p1.x, p1.y);
                    DOT_PAIR(wv.w, p1.z, p1.w);
                }
                slr[task] = sum;
            }
        }
        __syncthreads();

        // logits -> exp -> denominators (no max-sub: logits bounded, alpha invariant)
        float ex = 0.f;
        if (t < ESL) {
            float lg = 0.4f * abss + 0.6f * (slr[2 * s_e] + slr[2 * d_e + 1]);
            ex = __expf(lg);
            atomicAdd(&dsum[d_e], ex);
        }
        __syncthreads();
        if (t < ESL) atomicAdd(&Am[d_e * 32 + s_e], ex / dsum[d_e]);
        __syncthreads();

        // aggregate: hb = Am @ xl + cbias (+ LR except convs 2,5)
        {
            int arow = (w & 1) * 16 + m16;
            float4 u0 = *reinterpret_cast<const float4*>(&Am[arow * 32 + kc * 8]);
            float4 u1 = *reinterpret_cast<const float4*>(&Am[arow * 32 + kc * 8 + 4]);
            bf16x8 a;
            a[0] = (short)f2bf(u0.x); a[1] = (short)f2bf(u0.y);
            a[2] = (short)f2bf(u0.z); a[3] = (short)f2bf(u0.w);
            a[4] = (short)f2bf(u1.x); a[5] = (short)f2bf(u1.y);
            a[6] = (short)f2bf(u1.z); a[7] = (short)f2bf(u1.w);
            f32x4 acc2[4] = {};
            #pragma unroll
            for (int i = 0; i < 4; ++i) {
                int nt = (w >> 1) * 4 + i;
                bf16x8 b = *reinterpret_cast<const bf16x8*>(&xlT[(nt * 16 + m16) * XTS + kc * 8]);
                acc2[i] = __builtin_amdgcn_mfma_f32_16x16x32_bf16(a, b, acc2[i], 0, 0, 0);
            }
            const bool doact = (c % 3) < 2;
            #pragma unroll
            for (int i = 0; i < 4; ++i) {
                int col = (w >> 1) * 64 + i * 16 + m16;
                float cb = cbias[c * H + col];
                #pragma unroll
                for (int r = 0; r < 4; ++r) {
                    int row = (w & 1) * 16 + kc * 4 + r;
                    float v = acc2[i][r] + cb;
                    if (doact) v = lrelu(v, 0.01f);
                    hb[row * HSS + col] = f2bf(v);
                }
            }
        }
        __syncthreads();
    }

    // ---------------- pool + head MLP (f32, Am reused as scratch) ------------
    float* z  = Am;           // 136
    float* pa = Am + 144;
    float* pb = Am + 288;
    float* h1 = Am + 432;
    float* qa = Am + 576;
    float* qb = Am + 720;
    float* h2 = Am + 864;
    if (t < H) {
        float s = 0.f;
        for (int r = 0; r < P; ++r) s += u2f(((unsigned)hb[r * HSS + t]) << 16);
        z[t] = s;
    } else if (t < H + EX) {
        z[t] = extra[(long long)g * EX + (t - H)];
    }
    __syncthreads();
    {
        int j = t & 127, half = t >> 7;
        float a = half ? 0.f : bf0[j];
        int k0 = half ? 68 : 0, k1 = half ? 136 : 68;
        for (int k = k0; k < k1; ++k) a += z[k] * Wf0[k * H + j];
        (half ? pb : pa)[j] = a;
    }
    __syncthreads();
    if (t < H) h1[t] = lrelu(pa[t] + pb[t], 0.01f);
    __syncthreads();
    {
        int j = t & 127, half = t >> 7;
        float a = half ? 0.f : bf1[j];
        int k0 = half * 64, k1 = k0 + 64;
        for (int k = k0; k < k1; ++k) a += h1[k] * Wf1[k * H + j];
        (half ? qb : qa)[j] = a;
    }
    __syncthreads();
    if (t < H) h2[t] = lrelu(qa[t] + qb[t], 0.01f);
    __syncthreads();
    if (t < NOUT) {
        float a = bf2[t];
        for (int k = 0; k < H; ++k) a += h2[k] * Wf2[k * NOUT + t];
        out[(long long)g * NOUT + t] = a;
    }
}

extern "C" void kernel_launch(void* const* d_in, const int* in_sizes, int n_in,
                              void* d_out, int out_size, void* d_ws, size_t ws_size,
                              hipStream_t stream) {
    (void)in_sizes; (void)n_in; (void)out_size; (void)ws_size;
    const float* x     = (const float*)d_in[0];
    const int*   src   = (const int*)  d_in[1];
    const int*   dst   = (const int*)  d_in[2];
    const float* extra = (const float*)d_in[4];
    const float* W0    = (const float*)d_in[5];
    const float* b0    = (const float*)d_in[6];
    const float* W1    = (const float*)d_in[7];
    const float* b1    = (const float*)d_in[8];
    const float* Wl    = (const float*)d_in[9];
    const float* bl    = (const float*)d_in[10];
    const float* Wr    = (const float*)d_in[11];
    const float* br    = (const float*)d_in[12];
    const float* att   = (const float*)d_in[13];
    const float* cbias = (const float*)d_in[14];
    const float* Wf0   = (const float*)d_in[15];
    const float* bf0   = (const float*)d_in[16];
    const float* Wf1   = (const float*)d_in[17];
    const float* bf1   = (const float*)d_in[18];
    const float* Wf2   = (const float*)d_in[19];
    const float* bf2   = (const float*)d_in[20];
    unsigned short* wsb = (unsigned short*)d_ws;
    float* out = (float*)d_out;

    cvtw<<<848, 256, 0, stream>>>(W0, W1, Wl, Wr, wsb);
    gat_all<<<NG, 256, 0, stream>>>(x, src, dst, extra, b0, b1, bl, br, att, cbias,
                                    Wf0, bf0, Wf1, bf1, Wf2, bf2, wsb, out);
}

// Round 4
// 369.909 us; speedup vs baseline: 4.3322x; 1.0668x over previous
//
#include <hip/hip_runtime.h>

#define NG   4096
#define P    24
#define EPG  192
#define ESL  216
#define DIN  32
#define H    128
#define EX   8
#define NOUT 3
#define HSS  136   // f16 row stride for [32][H] tiles (272B rows)
#define XTS  36    // xlT row stride in ushorts (72B rows)

typedef _Float16 f16x8 __attribute__((ext_vector_type(8)));
typedef _Float16 h2    __attribute__((ext_vector_type(2)));
typedef float    f32x4 __attribute__((ext_vector_type(4)));

__device__ __forceinline__ unsigned short f2h(float v) {
    _Float16 h = (_Float16)v; unsigned short u; __builtin_memcpy(&u, &h, 2); return u;
}
__device__ __forceinline__ float h2f(unsigned short u) {
    _Float16 h; __builtin_memcpy(&h, &u, 2); return (float)h;
}
__device__ __forceinline__ unsigned pkadd(unsigned a, unsigned b) {
    h2 x, y; __builtin_memcpy(&x, &a, 4); __builtin_memcpy(&y, &b, 4);
    h2 z = x + y; unsigned r; __builtin_memcpy(&r, &z, 4); return r;
}
__device__ __forceinline__ float lrelu(float v, float s) { return v > 0.f ? v : v * s; }

// ---- prepass: convert/transpose weights to f16 in d_ws (ushort elems) ----
// W0T[128][32]@0 | W1T[128][128]@4096 | WLT[6][128][128]@20480 | WRT@118784
// WAL[6][16][128]@217088 (row0 = Wl@att) | WAR[6][16][128]@229376
// f32 consts @ushort 241664: bla[6], bra[6]
__global__ void cvtw(const float* __restrict__ W0, const float* __restrict__ W1,
                     const float* __restrict__ Wl, const float* __restrict__ Wr,
                     const float* __restrict__ att, const float* __restrict__ bl,
                     const float* __restrict__ br, unsigned short* __restrict__ ws) {
    int i = blockIdx.x * 256 + threadIdx.x;
    if (i < 217088) {
        float v;
        if (i < 4096)        { int n = i >> 5, k = i & 31;  v = W0[k * 128 + n]; }
        else if (i < 20480)  { int j = i - 4096;  int n = j >> 7, k = j & 127; v = W1[k * 128 + n]; }
        else if (i < 118784) { int j = i - 20480; int c = j >> 14, r = j & 16383;
                               int n = r >> 7, k = r & 127; v = Wl[c * 16384 + k * 128 + n]; }
        else                 { int j = i - 118784; int c = j >> 14, r = j & 16383;
                               int n = r >> 7, k = r & 127; v = Wr[c * 16384 + k * 128 + n]; }
        ws[i] = f2h(v);
    } else if (i < 241664) {
        int j = i - 217088;
        const float* W = (j < 12288) ? Wl : Wr;
        if (j >= 12288) j -= 12288;
        int c = j >> 11, r = j & 2047, row = r >> 7, k = r & 127;
        float v = 0.f;
        if (row == 0) {
            for (int q = 0; q < 128; ++q) v += W[c * 16384 + k * 128 + q] * att[c * 128 + q];
        }
        ws[i] = f2h(v);
    } else if (i < 241676) {
        int c = i - 241664;
        const float* B = (c < 6) ? bl : br;
        int cc = (c < 6) ? c : c - 6;
        float s = 0.f;
        for (int q = 0; q < 128; ++q) s += B[cc * 128 + q] * att[cc * 128 + q];
        ((float*)(ws + 241664))[c] = s;
    }
}

__global__ __launch_bounds__(256, 4) void gat_all(
    const float* __restrict__ x,
    const int*   __restrict__ src,
    const int*   __restrict__ dst,
    const float* __restrict__ extra,
    const float* __restrict__ b0,  const float* __restrict__ b1,
    const float* __restrict__ bl,  const float* __restrict__ br,
    const float* __restrict__ att, const float* __restrict__ cbias,
    const float* __restrict__ Wf0, const float* __restrict__ bf0,
    const float* __restrict__ Wf1, const float* __restrict__ bf1,
    const float* __restrict__ Wf2, const float* __restrict__ bf2,
    const unsigned short* __restrict__ wsb,
    float* __restrict__ out)
{
    // LDS: 8704*3 + 9216 + 4096 + 256 + 128 + 256 = 40064 B -> 4 blocks/CU
    __shared__ __align__(16) unsigned short hb [32 * HSS];
    __shared__ __align__(16) unsigned short xlb[32 * HSS];
    __shared__ __align__(16) unsigned short xrb[32 * HSS];
    __shared__ __align__(16) unsigned short xlT[128 * XTS];
    __shared__ __align__(16) float          Am[1024];      // [32][32] ex matrix / head scratch
    __shared__ __align__(16) unsigned int   att_h[64];     // att as packed f16 pairs
    __shared__ float dsum[32];
    __shared__ float snode[64];                            // sl[0..31], sr[32..63]

    const int g    = blockIdx.x;
    const int t    = threadIdx.x;
    const int lane = t & 63;
    const int w    = t >> 6;
    const int m16  = lane & 15;
    const int kc   = lane >> 4;
    const long long gn = (long long)g * P;

    const unsigned short* W0T = wsb;
    const unsigned short* W1T = wsb + 4096;
    const unsigned short* WLT = wsb + 20480;
    const unsigned short* WRT = wsb + 118784;
    const float* wsf = (const float*)(wsb + 241664);

    int s_e = 0, d_e = 0;
    if (t < ESL) {
        if (t < EPG) {
            s_e = src[(long long)g * EPG + t] - (int)gn;
            d_e = dst[(long long)g * EPG + t] - (int)gn;
        } else { s_e = d_e = t - EPG; }
    }

    // stage x (f16) into xlT as [32 nodes][32 feat], stride XTS
    if (t < 192) {
        float4 v = *reinterpret_cast<const float4*>(&x[gn * DIN + t * 4]);
        int n = t >> 3, k = (t & 7) * 4;
        *reinterpret_cast<ushort4*>(&xlT[n * XTS + k]) =
            make_ushort4(f2h(v.x), f2h(v.y), f2h(v.z), f2h(v.w));
    } else {
        int u = t - 192;
        int r = 24 + (u >> 3), k = (u & 7) * 4;
        *reinterpret_cast<ushort4*>(&xlT[r * XTS + k]) = make_ushort4(0, 0, 0, 0);
    }
    __syncthreads();

    // ---------------- init MLP layer 0: xlb = LR(x @ W0 + b0) ----------------
    {
        f32x4 acc[4] = {};
        f16x8 a = *reinterpret_cast<const f16x8*>(&xlT[((w & 1) * 16 + m16) * XTS + kc * 8]);
        #pragma unroll
        for (int i = 0; i < 4; ++i) {
            int nt = (w >> 1) * 4 + i;
            f16x8 b = *reinterpret_cast<const f16x8*>(&W0T[(nt * 16 + m16) * 32 + kc * 8]);
            acc[i] = __builtin_amdgcn_mfma_f32_16x16x32_f16(a, b, acc[i], 0, 0, 0);
        }
        #pragma unroll
        for (int i = 0; i < 4; ++i) {
            int col = (w >> 1) * 64 + i * 16 + m16;
            float bv = b0[col];
            #pragma unroll
            for (int r = 0; r < 4; ++r) {
                int row = (w & 1) * 16 + kc * 4 + r;
                xlb[row * HSS + col] = f2h(lrelu(acc[i][r] + bv, 0.01f));
            }
        }
    }
    __syncthreads();

    // ---------------- init MLP layer 1: hb = LR(xlb @ W1 + b1) ---------------
    {
        f32x4 acc[4] = {};
        for (int kt = 0; kt < 4; ++kt) {
            f16x8 a = *reinterpret_cast<const f16x8*>(&xlb[((w & 1) * 16 + m16) * HSS + kt * 32 + kc * 8]);
            #pragma unroll
            for (int i = 0; i < 4; ++i) {
                int nt = (w >> 1) * 4 + i;
                f16x8 b = *reinterpret_cast<const f16x8*>(&W1T[(nt * 16 + m16) * 128 + kt * 32 + kc * 8]);
                acc[i] = __builtin_amdgcn_mfma_f32_16x16x32_f16(a, b, acc[i], 0, 0, 0);
            }
        }
        #pragma unroll
        for (int i = 0; i < 4; ++i) {
            int col = (w >> 1) * 64 + i * 16 + m16;
            float bv = b1[col];
            #pragma unroll
            for (int r = 0; r < 4; ++r) {
                int row = (w & 1) * 16 + kc * 4 + r;
                hb[row * HSS + col] = f2h(lrelu(acc[i][r] + bv, 0.01f));
            }
        }
    }
    __syncthreads();

    // ---------------- 6 GATv2 convs (3 barriers each) ----------------
    for (int c = 0; c < 6; ++c) {
        // phase slot 1: zero Am/dsum, pack att, main matmul + slr-tile
        *reinterpret_cast<float4*>(&Am[t * 4]) = make_float4(0.f, 0.f, 0.f, 0.f);
        if (t < 32) dsum[t] = (t < P) ? 0.f : 1.0f;
        if (t < 64) att_h[t] = ((unsigned)f2h(att[c * H + 2 * t])) |
                               (((unsigned)f2h(att[c * H + 2 * t + 1])) << 16);

        const unsigned short* WT   = ((w & 1) ? WRT : WLT) + c * 16384;
        const unsigned short* WAX  = wsb + 217088 + ((w & 1) ? 12288 : 0) + c * 2048;
        const float*          bias = ((w & 1) ? br : bl) + c * H;
        f32x4 acc[8] = {};
        f32x4 acce[2] = {};
        for (int kt = 0; kt < 4; ++kt) {
            f16x8 a0 = *reinterpret_cast<const f16x8*>(&hb[(m16)      * HSS + kt * 32 + kc * 8]);
            f16x8 a1 = *reinterpret_cast<const f16x8*>(&hb[(16 + m16) * HSS + kt * 32 + kc * 8]);
            #pragma unroll
            for (int i = 0; i < 4; ++i) {
                int nt = (w >> 1) * 4 + i;
                f16x8 b = *reinterpret_cast<const f16x8*>(&WT[(nt * 16 + m16) * 128 + kt * 32 + kc * 8]);
                acc[i]     = __builtin_amdgcn_mfma_f32_16x16x32_f16(a0, b, acc[i],     0, 0, 0);
                acc[4 + i] = __builtin_amdgcn_mfma_f32_16x16x32_f16(a1, b, acc[4 + i], 0, 0, 0);
            }
            if (w >= 2) {   // sl/sr tile: B row0 = W@att, rows 1-15 zero
                f16x8 bx = *reinterpret_cast<const f16x8*>(&WAX[m16 * 128 + kt * 32 + kc * 8]);
                acce[0] = __builtin_amdgcn_mfma_f32_16x16x32_f16(a0, bx, acce[0], 0, 0, 0);
                acce[1] = __builtin_amdgcn_mfma_f32_16x16x32_f16(a1, bx, acce[1], 0, 0, 0);
            }
        }
        {
            unsigned short* XO = (w & 1) ? xrb : xlb;
            const bool isL = !(w & 1);
            #pragma unroll
            for (int mt = 0; mt < 2; ++mt)
            #pragma unroll
            for (int i = 0; i < 4; ++i) {
                int col = (w >> 1) * 64 + i * 16 + m16;
                float bv = bias[col];
                unsigned short ub[4];
                #pragma unroll
                for (int r = 0; r < 4; ++r) {
                    int row = mt * 16 + kc * 4 + r;
                    ub[r] = f2h(acc[mt * 4 + i][r] + bv);
                    XO[row * HSS + col] = ub[r];
                }
                if (isL)
                    *reinterpret_cast<ushort4*>(&xlT[col * XTS + mt * 16 + kc * 4]) =
                        make_ushort4(ub[0], ub[1], ub[2], ub[3]);
            }
            if (w >= 2 && m16 == 0) {       // col 0 of the slr tile = sl/sr
                float cst = (w == 2) ? wsf[c] : wsf[6 + c];
                float* dp = (w == 2) ? snode : (snode + 32);
                #pragma unroll
                for (int mt = 0; mt < 2; ++mt)
                #pragma unroll
                for (int r = 0; r < 4; ++r)
                    dp[mt * 16 + kc * 4 + r] = acce[mt][r] + cst;
            }
        }
        __syncthreads();

        // phase 2: per-edge logit + exp + scatter (ex into Am, denom into dsum)
        if (t < ESL) {
            const uint4* xa = reinterpret_cast<const uint4*>(&xlb[s_e * HSS]);
            const uint4* xb = reinterpret_cast<const uint4*>(&xrb[d_e * HSS]);
            const uint4* ap = reinterpret_cast<const uint4*>(att_h);
            float a0 = 0.f, a1 = 0.f, a2 = 0.f, a3 = 0.f;
            #pragma unroll 4
            for (int cc = 0; cc < 16; ++cc) {
                uint4 wa = xa[cc], wb = xb[cc], pp = ap[cc];
                unsigned u0 = pkadd(wa.x, wb.x) & 0x7fff7fffu;
                unsigned u1 = pkadd(wa.y, wb.y) & 0x7fff7fffu;
                unsigned u2 = pkadd(wa.z, wb.z) & 0x7fff7fffu;
                unsigned u3 = pkadd(wa.w, wb.w) & 0x7fff7fffu;
                asm volatile("v_dot2_f32_f16 %0, %1, %2, %0" : "+v"(a0) : "v"(u0), "v"(pp.x));
                asm volatile("v_dot2_f32_f16 %0, %1, %2, %0" : "+v"(a1) : "v"(u1), "v"(pp.y));
                asm volatile("v_dot2_f32_f16 %0, %1, %2, %0" : "+v"(a2) : "v"(u2), "v"(pp.z));
                asm volatile("v_dot2_f32_f16 %0, %1, %2, %0" : "+v"(a3) : "v"(u3), "v"(pp.w));
            }
            float abss = (a0 + a1) + (a2 + a3);
            float lg = fmaf(0.6f, snode[s_e] + snode[32 + d_e], 0.4f * abss);
            float ex = __expf(lg);
            atomicAdd(&Am[d_e * 32 + s_e], ex);
            atomicAdd(&dsum[d_e], ex);
        }
        __syncthreads();

        // phase 3: aggregate hb = (Am @ xl) / dsum + cbias (+ LR except convs 2,5)
        {
            int arow = (w & 1) * 16 + m16;
            float4 u0 = *reinterpret_cast<const float4*>(&Am[arow * 32 + kc * 8]);
            float4 u1 = *reinterpret_cast<const float4*>(&Am[arow * 32 + kc * 8 + 4]);
            f16x8 a;
            a[0] = (_Float16)u0.x; a[1] = (_Float16)u0.y;
            a[2] = (_Float16)u0.z; a[3] = (_Float16)u0.w;
            a[4] = (_Float16)u1.x; a[5] = (_Float16)u1.y;
            a[6] = (_Float16)u1.z; a[7] = (_Float16)u1.w;
            f32x4 acc2[4] = {};
            #pragma unroll
            for (int i = 0; i < 4; ++i) {
                int nt = (w >> 1) * 4 + i;
                f16x8 b = *reinterpret_cast<const f16x8*>(&xlT[(nt * 16 + m16) * XTS + kc * 8]);
                acc2[i] = __builtin_amdgcn_mfma_f32_16x16x32_f16(a, b, acc2[i], 0, 0, 0);
            }
            float inv[4];
            #pragma unroll
            for (int r = 0; r < 4; ++r)
                inv[r] = __builtin_amdgcn_rcpf(dsum[(w & 1) * 16 + kc * 4 + r]);
            const bool doact = (c % 3) < 2;
            #pragma unroll
            for (int i = 0; i < 4; ++i) {
                int col = (w >> 1) * 64 + i * 16 + m16;
                float cb = cbias[c * H + col];
                #pragma unroll
                for (int r = 0; r < 4; ++r) {
                    int row = (w & 1) * 16 + kc * 4 + r;
                    float v = fmaf(acc2[i][r], inv[r], cb);
                    if (doact) v = lrelu(v, 0.01f);
                    hb[row * HSS + col] = f2h(v);
                }
            }
        }
        __syncthreads();
    }

    // ---------------- pool + head MLP (f32, Am reused as scratch) ------------
    float* z  = Am;
    float* pa = Am + 144;
    float* pb = Am + 288;
    float* h1 = Am + 432;
    float* qa = Am + 576;
    float* qb = Am + 720;
    float* h2 = Am + 864;
    if (t < H) {
        float s = 0.f;
        for (int r = 0; r < P; ++r) s += h2f(hb[r * HSS + t]);
        z[t] = s;
    } else if (t < H + EX) {
        z[t] = extra[(long long)g * EX + (t - H)];
    }
    __syncthreads();
    {
        int j = t & 127, half = t >> 7;
        float a = half ? 0.f : bf0[j];
        int k0 = half ? 68 : 0, k1 = half ? 136 : 68;
        for (int k = k0; k < k1; ++k) a += z[k] * Wf0[k * H + j];
        (half ? pb : pa)[j] = a;
    }
    __syncthreads();
    if (t < H) h1[t] = lrelu(pa[t] + pb[t], 0.01f);
    __syncthreads();
    {
        int j = t & 127, half = t >> 7;
        float a = half ? 0.f : bf1[j];
        int k0 = half * 64, k1 = k0 + 64;
        for (int k = k0; k < k1; ++k) a += h1[k] * Wf1[k * H + j];
        (half ? qb : qa)[j] = a;
    }
    __syncthreads();
    if (t < H) h2[t] = lrelu(qa[t] + qb[t], 0.01f);
    __syncthreads();
    if (t < NOUT) {
        float a = bf2[t];
        for (int k = 0; k < H; ++k) a += h2[k] * Wf2[k * NOUT + t];
        out[(long long)g * NOUT + t] = a;
    }
}

extern "C" void kernel_launch(void* const* d_in, const int* in_sizes, int n_in,
                              void* d_out, int out_size, void* d_ws, size_t ws_size,
                              hipStream_t stream) {
    (void)in_sizes; (void)n_in; (void)out_size; (void)ws_size;
    const float* x     = (const float*)d_in[0];
    const int*   src   = (const int*)  d_in[1];
    const int*   dst   = (const int*)  d_in[2];
    const float* extra = (const float*)d_in[4];
    const float* W0    = (const float*)d_in[5];
    const float* b0    = (const float*)d_in[6];
    const float* W1    = (const float*)d_in[7];
    const float* b1    = (const float*)d_in[8];
    const float* Wl    = (const float*)d_in[9];
    const float* bl    = (const float*)d_in[10];
    const float* Wr    = (const float*)d_in[11];
    const float* br    = (const float*)d_in[12];
    const float* att   = (const float*)d_in[13];
    const float* cbias = (const float*)d_in[14];
    const float* Wf0   = (const float*)d_in[15];
    const float* bf0   = (const float*)d_in[16];
    const float* Wf1   = (const float*)d_in[17];
    const float* bf1   = (const float*)d_in[18];
    const float* Wf2   = (const float*)d_in[19];
    const float* bf2   = (const float*)d_in[20];
    unsigned short* wsb = (unsigned short*)d_ws;
    float* out = (float*)d_out;

    cvtw<<<945, 256, 0, stream>>>(W0, W1, Wl, Wr, att, bl, br, wsb);
    gat_all<<<NG, 256, 0, stream>>>(x, src, dst, extra, b0, b1, bl, br, att, cbias,
                                    Wf0, bf0, Wf1, bf1, Wf2, bf2, wsb, out);
}